// Round 4
// baseline (885.423 us; speedup 1.0000x reference)
//
#include <hip/hip_runtime.h>
#include <hip/hip_bf16.h>

#define B_  2
#define S_  2048
#define H_  1024
#define NH_ 16
#define HD_ 64

typedef __bf16 bf16_t;
typedef __attribute__((ext_vector_type(4))) __bf16 bf16x4;
typedef __attribute__((ext_vector_type(8))) __bf16 bf16x8;
typedef __attribute__((ext_vector_type(4))) float f32x4;

__device__ __forceinline__ void gld_lds16(const bf16_t* g, bf16_t* l) {
    __builtin_amdgcn_global_load_lds(
        (const __attribute__((address_space(1))) unsigned int*)g,
        (__attribute__((address_space(3))) unsigned int*)l, 16, 0, 0);
}

// ---------------------------------------------------------------------------
// Kernel 0: cast X and Wq/Wk/Wv to bf16 once (~10us).
// ---------------------------------------------------------------------------
__global__ __launch_bounds__(256) void cast_bf16(
    const float* __restrict__ X, const float* __restrict__ Wq,
    const float* __restrict__ Wk, const float* __restrict__ Wv,
    bf16_t* __restrict__ Xb, bf16_t* __restrict__ Wb)
{
    const size_t XN = (size_t)B_ * S_ * H_;           // 4,194,304
    size_t i4 = ((size_t)blockIdx.x * 256 + threadIdx.x) * 4;
    const float* src;
    bf16_t* dst;
    if (i4 < XN) {
        src = X + i4; dst = Xb + i4;
    } else {
        size_t j = i4 - XN;                           // [0, 3M)
        int wsel = (int)(j >> 20);                    // 1M floats per W
        const float* Wp = wsel == 0 ? Wq : (wsel == 1 ? Wk : Wv);
        src = Wp + (j & 1048575); dst = Wb + j;
    }
    float4 v = *(const float4*)src;
    bf16x4 o = { (bf16_t)v.x, (bf16_t)v.y, (bf16_t)v.z, (bf16_t)v.w };
    *(bf16x4*)dst = o;
}

// ---------------------------------------------------------------------------
// Kernel 1: QKV projection, catalog 2-phase double-buffer (T3-min + T4):
//   barrier at END of iter; stage tile kc+1 issued at TOP of iter kc
//   (immediately after the barrier that guarantees all waves finished
//   reading buf^1 = tile kc-1's buffer). Round-3 bug: staging was issued
//   BEFORE the barrier -> gld_lds writes could land while a lagging wave
//   was still ds_reading tile kc-1 from the same buffer (race, absmax 2e-2).
//   Loads still overlap the full ds_read+MFMA phase; vmcnt(0) at iter end.
// ---------------------------------------------------------------------------
__global__ __launch_bounds__(256, 2) void qkv_gemm(
    const bf16_t* __restrict__ Xb, const bf16_t* __restrict__ Wb,
    const float* __restrict__ bq, const float* __restrict__ bk,
    const float* __restrict__ bv,
    bf16_t* __restrict__ qbuf, bf16_t* __restrict__ kbuf, bf16_t* __restrict__ vbuf)
{
    const int which = blockIdx.z;
    const bf16_t* W  = Wb + (size_t)which * H_ * H_;
    const float* bias = which == 0 ? bq : (which == 1 ? bk : bv);
    bf16_t* out       = which == 0 ? qbuf : (which == 1 ? kbuf : vbuf);
    const float scale = which == 0 ? 0.125f : 1.0f;

    const int m0 = blockIdx.x * 128;
    const int n0 = blockIdx.y * 128;
    const int t    = threadIdx.x;
    const int lane = t & 63;
    const int w    = t >> 6;
    const int wr   = w >> 1, wc = w & 1;
    const int lo   = lane & 15, g = lane >> 4;

    __shared__ bf16_t As[2][128 * 64];   // 2 x 16KB
    __shared__ bf16_t Bs[2][128 * 64];   // 2 x 16KB  (total 64KB)

    const int srow = w * 8 + (lane >> 3);
    const int scol = (lane & 7) * 8;
    const bf16_t* ga = Xb + (size_t)(m0 + srow) * H_ + scol;
    const bf16_t* gb = W  + (size_t)(n0 + srow) * H_ + scol;

    f32x4 acc[4][4];
#pragma unroll
    for (int mt = 0; mt < 4; ++mt)
#pragma unroll
        for (int nt = 0; nt < 4; ++nt)
            acc[mt][nt] = (f32x4){0.f, 0.f, 0.f, 0.f};

    // prologue: stage k-tile 0 into buf 0, wait, barrier
#pragma unroll
    for (int p = 0; p < 4; ++p) {
        gld_lds16(ga + (size_t)p * 32 * H_, &As[0][p * 2048 + w * 512]);
        gld_lds16(gb + (size_t)p * 32 * H_, &Bs[0][p * 2048 + w * 512]);
    }
    asm volatile("s_waitcnt vmcnt(0)" ::: "memory");
    __builtin_amdgcn_s_barrier();

    for (int kc = 0; kc < 16; ++kc) {
        const int cur = kc & 1;
        // stage next tile into buf^1 — safe: the barrier we just crossed
        // post-dates every wave's reads of buf^1 (consumed by MFMA last iter)
        if (kc < 15) {
#pragma unroll
            for (int p = 0; p < 4; ++p) {
                gld_lds16(ga + (size_t)p * 32 * H_ + (kc + 1) * 64,
                          &As[cur ^ 1][p * 2048 + w * 512]);
                gld_lds16(gb + (size_t)p * 32 * H_ + (kc + 1) * 64,
                          &Bs[cur ^ 1][p * 2048 + w * 512]);
            }
        }

        // compute on buf[cur] (loads for kc+1 in flight underneath)
        bf16x8 a0[4], a1[4];
#pragma unroll
        for (int mt = 0; mt < 4; ++mt) {
            a0[mt] = *(const bf16x8*)&As[cur][(wr * 64 + mt * 16 + lo) * 64 + g * 8];
            a1[mt] = *(const bf16x8*)&As[cur][(wr * 64 + mt * 16 + lo) * 64 + g * 8 + 32];
        }
        __builtin_amdgcn_s_setprio(1);
#pragma unroll
        for (int nt = 0; nt < 4; ++nt) {
            bf16x8 b0 = *(const bf16x8*)&Bs[cur][(wc * 64 + nt * 16 + lo) * 64 + g * 8];
            bf16x8 b1 = *(const bf16x8*)&Bs[cur][(wc * 64 + nt * 16 + lo) * 64 + g * 8 + 32];
#pragma unroll
            for (int mt = 0; mt < 4; ++mt) {
                acc[mt][nt] = __builtin_amdgcn_mfma_f32_16x16x32_bf16(a0[mt], b0, acc[mt][nt], 0, 0, 0);
                acc[mt][nt] = __builtin_amdgcn_mfma_f32_16x16x32_bf16(a1[mt], b1, acc[mt][nt], 0, 0, 0);
            }
        }
        __builtin_amdgcn_s_setprio(0);

        // end of iter: next tile's loads landed; all waves' reads of
        // buf[cur] retired (MFMA consumed them) before barrier arrival.
        if (kc < 15) {
            asm volatile("s_waitcnt vmcnt(0)" ::: "memory");
            __builtin_amdgcn_s_barrier();
        }
    }

    // epilogue: +bias, *scale, cast bf16, scatter to [B][NH][S][HD]
#pragma unroll
    for (int nt = 0; nt < 4; ++nt) {
        int n  = n0 + wc * 64 + nt * 16 + lo;
        int hh = n >> 6, d = n & 63;
        float bv_ = bias[n];
#pragma unroll
        for (int mt = 0; mt < 4; ++mt) {
#pragma unroll
            for (int r = 0; r < 4; ++r) {
                int m = m0 + wr * 64 + mt * 16 + g * 4 + r;
                int b = m >> 11, s = m & 2047;
                out[(((size_t)(b * NH_ + hh) * S_) + s) * HD_ + d] =
                    (bf16_t)((acc[mt][nt][r] + bv_) * scale);
            }
        }
    }
}

// ---------------------------------------------------------------------------
// Kernel 2: flash attention (unchanged from round 3; the round-3 failure
// was the qkv race). rel_pos streamed through a double-buffered LDS stage
// with coalesced float4 loads; T14 split (global->reg at phase c-1,
// ds_write at phase c, consume at phase c+1). Rel rows stride 68 floats
// (2-way/free banks both sides). K/V reg-staged one chunk ahead; raw
// s_barrier + lgkmcnt(0) only (no vmcnt drain at barriers).
// ---------------------------------------------------------------------------
__global__ __launch_bounds__(256, 2) void attn(
    const bf16_t* __restrict__ qbuf, const bf16_t* __restrict__ kbuf,
    const bf16_t* __restrict__ vbuf,
    const float* __restrict__ mask, const float* __restrict__ rel,
    float* __restrict__ out)
{
    // XCD-aware decode: 128 consecutive works per XCD = 4 (b,h) pairs;
    // K+V = 2MB per XCD -> L2/L3 resident.
    const int bid  = blockIdx.x;                   // 0..1023
    const int work = ((bid & 7) << 7) | (bid >> 3);
    const int q0 = (work & 31) * 64;
    const int h  = (work >> 5) & 15;
    const int b  = work >> 9;

    const int t    = threadIdx.x;
    const int lane = t & 63;
    const int w    = t >> 6;
    const int lo   = lane & 15;
    const int g    = lane >> 4;

    __shared__ bf16_t QPs[64 * 72];   // Q tile; re-used as per-wave P strips
    __shared__ bf16_t Ks [64 * 72];
    __shared__ bf16_t VTs[64 * 72];   // V^T, XOR-swizzled (s' = s ^ (d&56))
    __shared__ float  Ms [S_];        // mask row for this batch (8KB)
    __shared__ float  Rs [2][64 * 68]; // rel tile double buffer (2 x 17KB)

    const bf16_t* qg = qbuf + ((size_t)(b * NH_ + h) * S_ + q0) * HD_;
    const bf16_t* kg = kbuf + (size_t)(b * NH_ + h) * S_ * HD_;
    const bf16_t* vg = vbuf + (size_t)(b * NH_ + h) * S_ * HD_;
    const float*  relg  = rel + ((size_t)((b * NH_ + h) * S_ + q0)) * S_;
    const float*  maskg = mask + (size_t)b * S_;

    // K/V staging slot: rows r0, r0+32; cols c8..c8+7
    const int r0 = t >> 3;            // 0..31
    const int c8 = (t & 7) * 8;
    // rel staging slot: row rrow, 64B run at col rc16
    const int rrow = t >> 2;          // 0..63
    const int rc16 = (t & 3) * 16;    // 0,16,32,48

    // ---- prologue ----
    uint4 kv0 = *(const uint4*)&kg[(size_t)r0 * 64 + c8];
    uint4 kv1 = *(const uint4*)&kg[(size_t)(r0 + 32) * 64 + c8];
    uint4 vv0 = *(const uint4*)&vg[(size_t)r0 * 64 + c8];
    uint4 vv1 = *(const uint4*)&vg[(size_t)(r0 + 32) * 64 + c8];

    float4 rr[4];
#pragma unroll
    for (int p = 0; p < 4; ++p)
        rr[p] = *(const float4*)&relg[(size_t)rrow * S_ + rc16 + p * 4];

    uint4  qv0 = *(const uint4*)&qg[(size_t)r0 * 64 + c8];
    uint4  qv1 = *(const uint4*)&qg[(size_t)(r0 + 32) * 64 + c8];
    float4 mv0 = *(const float4*)&maskg[t * 8];
    float4 mv1 = *(const float4*)&maskg[t * 8 + 4];

    *(uint4*)&QPs[r0 * 72 + c8]        = qv0;
    *(uint4*)&QPs[(r0 + 32) * 72 + c8] = qv1;
    *(float4*)&Ms[t * 8]     = mv0;
    *(float4*)&Ms[t * 8 + 4] = mv1;

    // rel(0) -> Rs[0]; then issue rel(1) loads (full-chunk flight)
#pragma unroll
    for (int p = 0; p < 4; ++p)
        *(float4*)&Rs[0][rrow * 68 + rc16 + p * 4] = rr[p];
#pragma unroll
    for (int p = 0; p < 4; ++p)
        rr[p] = *(const float4*)&relg[(size_t)rrow * S_ + 64 + rc16 + p * 4];

    asm volatile("s_waitcnt lgkmcnt(0)" ::: "memory");
    __builtin_amdgcn_s_barrier();

    // Q A-frags (q pre-scaled by 1/8 in the GEMM). Wave-private strips.
    bf16x8 aq0 = *(const bf16x8*)&QPs[(w * 16 + lo) * 72 + g * 8];
    bf16x8 aq1 = *(const bf16x8*)&QPs[(w * 16 + lo) * 72 + g * 8 + 32];

    float mi[4], li[4];
    f32x4 accO[4];
#pragma unroll
    for (int r = 0; r < 4; ++r) { mi[r] = -1e30f; li[r] = 0.f; }
#pragma unroll
    for (int dt = 0; dt < 4; ++dt) accO[dt] = (f32x4){0.f, 0.f, 0.f, 0.f};

    const int qrow = w * 16 + g * 4;  // +r

    for (int kc = 0; kc < 32; ++kc) {
        // [write phase] K/V tile (counted vmcnt by compiler on kv regs)
        *(uint4*)&Ks[r0 * 72 + c8]        = kv0;
        *(uint4*)&Ks[(r0 + 32) * 72 + c8] = kv1;
        {
            const bf16_t* vp0 = (const bf16_t*)&vv0;
            const bf16_t* vp1 = (const bf16_t*)&vv1;
            int sw0 = r0 ^ c8, sw1 = (r0 + 32) ^ c8;
#pragma unroll
            for (int j = 0; j < 8; ++j) {
                VTs[(c8 + j) * 72 + sw0] = vp0[j];
                VTs[(c8 + j) * 72 + sw1] = vp1[j];
            }
        }
        // rel(kc+1) regs -> Rs[(kc+1)&1]; issue rel(kc+2)
        if (kc < 31) {
            float* Rd = &Rs[(kc + 1) & 1][rrow * 68 + rc16];
#pragma unroll
            for (int p = 0; p < 4; ++p)
                *(float4*)&Rd[p * 4] = rr[p];
            const int kn = (kc + 2 <= 31) ? kc + 2 : 31;
#pragma unroll
            for (int p = 0; p < 4; ++p)
                rr[p] = *(const float4*)&relg[(size_t)rrow * S_ + kn * 64 + rc16 + p * 4];
        }
        // issue next K/V chunk loads (stay in flight across barrier+compute)
        {
            const int kn = (kc < 31) ? kc + 1 : kc;
            const bf16_t* kgn = kg + (size_t)kn * 64 * 64;
            const bf16_t* vgn = vg + (size_t)kn * 64 * 64;
            kv0 = *(const uint4*)&kgn[(size_t)r0 * 64 + c8];
            kv1 = *(const uint4*)&kgn[(size_t)(r0 + 32) * 64 + c8];
            vv0 = *(const uint4*)&vgn[(size_t)r0 * 64 + c8];
            vv1 = *(const uint4*)&vgn[(size_t)(r0 + 32) * 64 + c8];
        }

        asm volatile("s_waitcnt lgkmcnt(0)" ::: "memory");  // drain ds_writes
        __builtin_amdgcn_s_barrier();                       // tile visible

        // [QK phase]
        f32x4 sc[4];
        __builtin_amdgcn_s_setprio(1);
#pragma unroll
        for (int nt = 0; nt < 4; ++nt) {
            bf16x8 b0 = *(const bf16x8*)&Ks[(nt * 16 + lo) * 72 + g * 8];
            bf16x8 b1 = *(const bf16x8*)&Ks[(nt * 16 + lo) * 72 + g * 8 + 32];
            f32x4 z = (f32x4){0.f, 0.f, 0.f, 0.f};
            z = __builtin_amdgcn_mfma_f32_16x16x32_bf16(aq0, b0, z, 0, 0, 0);
            z = __builtin_amdgcn_mfma_f32_16x16x32_bf16(aq1, b1, z, 0, 0, 0);
            sc[nt] = z;
        }
        __builtin_amdgcn_s_setprio(0);

        // scores = qk + mask(LDS) + rel(LDS, staged last chunk)
        const float* Rc = &Rs[kc & 1][0];
        float sv[4][4];
#pragma unroll
        for (int nt = 0; nt < 4; ++nt) {
            float mk = Ms[kc * 64 + nt * 16 + lo];
#pragma unroll
            for (int r = 0; r < 4; ++r)
                sv[r][nt] = sc[nt][r] + mk + Rc[(qrow + r) * 68 + nt * 16 + lo];
        }

        // online softmax; P into this wave's swizzled strip
        bf16_t* Pw = &QPs[w * 16 * 72];
#pragma unroll
        for (int r = 0; r < 4; ++r) {
            float vmax = fmaxf(fmaxf(sv[r][0], sv[r][1]), fmaxf(sv[r][2], sv[r][3]));
#pragma unroll
            for (int mk2 = 1; mk2 < 16; mk2 <<= 1)
                vmax = fmaxf(vmax, __shfl_xor(vmax, mk2, 16));
            float mnew  = fmaxf(mi[r], vmax);
            float alpha = __expf(mi[r] - mnew);
            float rsum = 0.f;
#pragma unroll
            for (int nt = 0; nt < 4; ++nt) {
                float p = __expf(sv[r][nt] - mnew);
                sv[r][nt] = p;
                rsum += p;
            }
#pragma unroll
            for (int mk2 = 1; mk2 < 16; mk2 <<= 1)
                rsum += __shfl_xor(rsum, mk2, 16);
            li[r] = li[r] * alpha + rsum;
            mi[r] = mnew;
#pragma unroll
            for (int dt = 0; dt < 4; ++dt) accO[dt][r] *= alpha;
#pragma unroll
            for (int nt = 0; nt < 4; ++nt)
                Pw[(g * 4 + r) * 72 + ((nt * 16 + lo) ^ (g * 8))] = (bf16_t)sv[r][nt];
        }
        // no barrier: P strip is wave-private; in-wave ds order via lgkmcnt.

        // [PV phase]
        bf16x8 pa0 = *(const bf16x8*)&Pw[lo * 72 + ((g * 8)       ^ ((lo >> 2) * 8))];
        bf16x8 pa1 = *(const bf16x8*)&Pw[lo * 72 + (((4 + g) * 8) ^ ((lo >> 2) * 8))];
        __builtin_amdgcn_s_setprio(1);
#pragma unroll
        for (int dt = 0; dt < 4; ++dt) {
            int d = dt * 16 + lo;
            bf16x8 v0 = *(const bf16x8*)&VTs[d * 72 + ((g * 8)       ^ (d & 56))];
            bf16x8 v1 = *(const bf16x8*)&VTs[d * 72 + (((4 + g) * 8) ^ (d & 56))];
            accO[dt] = __builtin_amdgcn_mfma_f32_16x16x32_bf16(pa0, v0, accO[dt], 0, 0, 0);
            accO[dt] = __builtin_amdgcn_mfma_f32_16x16x32_bf16(pa1, v1, accO[dt], 0, 0, 0);
        }
        __builtin_amdgcn_s_setprio(0);

        // reads retired (MFMA consumption + explicit lgkm) before next stage
        asm volatile("s_waitcnt lgkmcnt(0)" ::: "memory");
        __builtin_amdgcn_s_barrier();
    }

    // epilogue: out[b][s][h*64+d] = O / l
#pragma unroll
    for (int dt = 0; dt < 4; ++dt) {
        int d = dt * 16 + lo;
#pragma unroll
        for (int r = 0; r < 4; ++r) {
            int row = q0 + w * 16 + g * 4 + r;
            out[((size_t)(b * S_ + row)) * H_ + h * HD_ + d] = accO[dt][r] / li[r];
        }
    }
}

extern "C" void kernel_launch(void* const* d_in, const int* in_sizes, int n_in,
                              void* d_out, int out_size, void* d_ws, size_t ws_size,
                              hipStream_t stream) {
    const float* hs   = (const float*)d_in[0];
    const float* mask = (const float*)d_in[1];
    const float* rel  = (const float*)d_in[2];
    const float* Wq   = (const float*)d_in[3];
    const float* bq   = (const float*)d_in[4];
    const float* Wk   = (const float*)d_in[5];
    const float* bk   = (const float*)d_in[6];
    const float* Wv   = (const float*)d_in[7];
    const float* bv   = (const float*)d_in[8];
    float* out = (float*)d_out;

    const size_t qkv_elems = (size_t)B_ * NH_ * S_ * HD_;  // 4,194,304
    bf16_t* qbuf = (bf16_t*)d_ws;
    bf16_t* kbuf = qbuf + qkv_elems;
    bf16_t* vbuf = kbuf + qkv_elems;
    bf16_t* Xb   = vbuf + qkv_elems;               // 4M elems
    bf16_t* Wb   = Xb   + qkv_elems;               // 3M elems (Wq,Wk,Wv)

    cast_bf16<<<7168, 256, 0, stream>>>(hs, Wq, Wk, Wv, Xb, Wb);
    qkv_gemm<<<dim3(32, 8, 3), 256, 0, stream>>>(Xb, Wb, bq, bk, bv,
                                                 qbuf, kbuf, vbuf);
    attn<<<1024, 256, 0, stream>>>(qbuf, kbuf, vbuf, mask, rel, out);
}

// Round 5
// 817.448 us; speedup vs baseline: 1.0832x; 1.0832x over previous
//
#include <hip/hip_runtime.h>
#include <hip/hip_bf16.h>

#define B_  2
#define S_  2048
#define H_  1024
#define NH_ 16
#define HD_ 64

typedef __bf16 bf16_t;
typedef __attribute__((ext_vector_type(4))) __bf16 bf16x4;
typedef __attribute__((ext_vector_type(8))) __bf16 bf16x8;
typedef __attribute__((ext_vector_type(4))) float f32x4;

__device__ __forceinline__ void gld_lds16(const bf16_t* g, bf16_t* l) {
    __builtin_amdgcn_global_load_lds(
        (const __attribute__((address_space(1))) unsigned int*)g,
        (__attribute__((address_space(3))) unsigned int*)l, 16, 0, 0);
}

// ---------------------------------------------------------------------------
// Kernel 0: cast X and Wq/Wk/Wv to bf16 once (~10us).
// ---------------------------------------------------------------------------
__global__ __launch_bounds__(256) void cast_bf16(
    const float* __restrict__ X, const float* __restrict__ Wq,
    const float* __restrict__ Wk, const float* __restrict__ Wv,
    bf16_t* __restrict__ Xb, bf16_t* __restrict__ Wb)
{
    const size_t XN = (size_t)B_ * S_ * H_;           // 4,194,304
    size_t i4 = ((size_t)blockIdx.x * 256 + threadIdx.x) * 4;
    const float* src;
    bf16_t* dst;
    if (i4 < XN) {
        src = X + i4; dst = Xb + i4;
    } else {
        size_t j = i4 - XN;                           // [0, 3M)
        int wsel = (int)(j >> 20);                    // 1M floats per W
        const float* Wp = wsel == 0 ? Wq : (wsel == 1 ? Wk : Wv);
        src = Wp + (j & 1048575); dst = Wb + j;
    }
    float4 v = *(const float4*)src;
    bf16x4 o = { (bf16_t)v.x, (bf16_t)v.y, (bf16_t)v.z, (bf16_t)v.w };
    *(bf16x4*)dst = o;
}

// ---------------------------------------------------------------------------
// Kernel 1: QKV projection, catalog 2-phase double-buffer (unchanged from
// round 4, which passed): barrier at END of iter; stage kc+1 at TOP of iter
// kc (after the barrier that post-dates all reads of that buffer).
// ---------------------------------------------------------------------------
__global__ __launch_bounds__(256, 2) void qkv_gemm(
    const bf16_t* __restrict__ Xb, const bf16_t* __restrict__ Wb,
    const float* __restrict__ bq, const float* __restrict__ bk,
    const float* __restrict__ bv,
    bf16_t* __restrict__ qbuf, bf16_t* __restrict__ kbuf, bf16_t* __restrict__ vbuf)
{
    const int which = blockIdx.z;
    const bf16_t* W  = Wb + (size_t)which * H_ * H_;
    const float* bias = which == 0 ? bq : (which == 1 ? bk : bv);
    bf16_t* out       = which == 0 ? qbuf : (which == 1 ? kbuf : vbuf);
    const float scale = which == 0 ? 0.125f : 1.0f;

    const int m0 = blockIdx.x * 128;
    const int n0 = blockIdx.y * 128;
    const int t    = threadIdx.x;
    const int lane = t & 63;
    const int w    = t >> 6;
    const int wr   = w >> 1, wc = w & 1;
    const int lo   = lane & 15, g = lane >> 4;

    __shared__ bf16_t As[2][128 * 64];   // 2 x 16KB
    __shared__ bf16_t Bs[2][128 * 64];   // 2 x 16KB  (total 64KB)

    const int srow = w * 8 + (lane >> 3);
    const int scol = (lane & 7) * 8;
    const bf16_t* ga = Xb + (size_t)(m0 + srow) * H_ + scol;
    const bf16_t* gb = W  + (size_t)(n0 + srow) * H_ + scol;

    f32x4 acc[4][4];
#pragma unroll
    for (int mt = 0; mt < 4; ++mt)
#pragma unroll
        for (int nt = 0; nt < 4; ++nt)
            acc[mt][nt] = (f32x4){0.f, 0.f, 0.f, 0.f};

    // prologue: stage k-tile 0 into buf 0, wait, barrier
#pragma unroll
    for (int p = 0; p < 4; ++p) {
        gld_lds16(ga + (size_t)p * 32 * H_, &As[0][p * 2048 + w * 512]);
        gld_lds16(gb + (size_t)p * 32 * H_, &Bs[0][p * 2048 + w * 512]);
    }
    asm volatile("s_waitcnt vmcnt(0)" ::: "memory");
    __builtin_amdgcn_s_barrier();

    for (int kc = 0; kc < 16; ++kc) {
        const int cur = kc & 1;
        if (kc < 15) {
#pragma unroll
            for (int p = 0; p < 4; ++p) {
                gld_lds16(ga + (size_t)p * 32 * H_ + (kc + 1) * 64,
                          &As[cur ^ 1][p * 2048 + w * 512]);
                gld_lds16(gb + (size_t)p * 32 * H_ + (kc + 1) * 64,
                          &Bs[cur ^ 1][p * 2048 + w * 512]);
            }
        }

        bf16x8 a0[4], a1[4];
#pragma unroll
        for (int mt = 0; mt < 4; ++mt) {
            a0[mt] = *(const bf16x8*)&As[cur][(wr * 64 + mt * 16 + lo) * 64 + g * 8];
            a1[mt] = *(const bf16x8*)&As[cur][(wr * 64 + mt * 16 + lo) * 64 + g * 8 + 32];
        }
        __builtin_amdgcn_s_setprio(1);
#pragma unroll
        for (int nt = 0; nt < 4; ++nt) {
            bf16x8 b0 = *(const bf16x8*)&Bs[cur][(wc * 64 + nt * 16 + lo) * 64 + g * 8];
            bf16x8 b1 = *(const bf16x8*)&Bs[cur][(wc * 64 + nt * 16 + lo) * 64 + g * 8 + 32];
#pragma unroll
            for (int mt = 0; mt < 4; ++mt) {
                acc[mt][nt] = __builtin_amdgcn_mfma_f32_16x16x32_bf16(a0[mt], b0, acc[mt][nt], 0, 0, 0);
                acc[mt][nt] = __builtin_amdgcn_mfma_f32_16x16x32_bf16(a1[mt], b1, acc[mt][nt], 0, 0, 0);
            }
        }
        __builtin_amdgcn_s_setprio(0);

        if (kc < 15) {
            asm volatile("s_waitcnt vmcnt(0)" ::: "memory");
            __builtin_amdgcn_s_barrier();
        }
    }

    // epilogue: +bias, *scale, cast bf16, scatter to [B][NH][S][HD]
#pragma unroll
    for (int nt = 0; nt < 4; ++nt) {
        int n  = n0 + wc * 64 + nt * 16 + lo;
        int hh = n >> 6, d = n & 63;
        float bv_ = bias[n];
#pragma unroll
        for (int mt = 0; mt < 4; ++mt) {
#pragma unroll
            for (int r = 0; r < 4; ++r) {
                int m = m0 + wr * 64 + mt * 16 + g * 4 + r;
                int b = m >> 11, s = m & 2047;
                out[(((size_t)(b * NH_ + hh) * S_) + s) * HD_ + d] =
                    (bf16_t)((acc[mt][nt][r] + bv_) * scale);
            }
        }
    }
}

// ---------------------------------------------------------------------------
// Kernel 2: flash attention — round-2 structure (best measured: reg-prefetch
// rel, no rel LDS stage) with two changes:
//  - occupancy 4 blocks/CU: LDS back to 35.2KB, __launch_bounds__(256,4).
//    r0 counters showed the kernel ~70% idle (latency-bound) -> TLP is the
//    medicine; r4's 69KB/2-blocks config was the regression.
//  - V^T staging halved: thread loads V row pair (2q, 2q+1) and writes 8
//    ds_write_b32 (pair-packed) instead of 16 ds_write_b16. Swizzle
//    s' = s ^ (d&56) preserved; pair stays adjacent (d&56 has no bit0).
//    Write banks: (4j + (q ^ 4a)) mod 32 -> 2-way (free). Read side
//    byte-identical to round 2.
// ---------------------------------------------------------------------------
__global__ __launch_bounds__(256, 4) void attn(
    const bf16_t* __restrict__ qbuf, const bf16_t* __restrict__ kbuf,
    const bf16_t* __restrict__ vbuf,
    const float* __restrict__ mask, const float* __restrict__ rel,
    float* __restrict__ out)
{
    // XCD-aware decode: 128 consecutive works per XCD = 4 (b,h) pairs;
    // K+V = 2MB per XCD -> L2-resident.
    const int bid  = blockIdx.x;                   // 0..1023
    const int work = ((bid & 7) << 7) | (bid >> 3);
    const int q0 = (work & 31) * 64;
    const int h  = (work >> 5) & 15;
    const int b  = work >> 9;

    const int t    = threadIdx.x;
    const int lane = t & 63;
    const int w    = t >> 6;
    const int lo   = lane & 15;
    const int g    = lane >> 4;

    __shared__ bf16_t QPs[64 * 72];   // Q tile; re-used as per-wave P strips
    __shared__ bf16_t Ks [64 * 72];
    __shared__ bf16_t VTs[64 * 72];   // V^T, XOR-swizzled (s' = s ^ (d&56))
    __shared__ float  Ms [S_];        // mask row for this batch (8KB)

    const bf16_t* qg = qbuf + ((size_t)(b * NH_ + h) * S_ + q0) * HD_;
    const bf16_t* kg = kbuf + (size_t)(b * NH_ + h) * S_ * HD_;
    const bf16_t* vg = vbuf + (size_t)(b * NH_ + h) * S_ * HD_;
    const float*  relg  = rel + ((size_t)((b * NH_ + h) * S_ + q0)) * S_;
    const float*  maskg = mask + (size_t)b * S_;

    // staging slots: K rows r0, r0+32; V row pair (2*r0, 2*r0+1); cols c8..c8+7
    const int r0 = t >> 3;            // 0..31
    const int c8 = (t & 7) * 8;

    // ---- prologue ----
    uint4 kv0 = *(const uint4*)&kg[(size_t)r0 * 64 + c8];
    uint4 kv1 = *(const uint4*)&kg[(size_t)(r0 + 32) * 64 + c8];
    uint4 vv0 = *(const uint4*)&vg[(size_t)(2 * r0) * 64 + c8];
    uint4 vv1 = *(const uint4*)&vg[(size_t)(2 * r0 + 1) * 64 + c8];

    uint4  qv0 = *(const uint4*)&qg[(size_t)r0 * 64 + c8];
    uint4  qv1 = *(const uint4*)&qg[(size_t)(r0 + 32) * 64 + c8];
    float4 mv0 = *(const float4*)&maskg[t * 8];
    float4 mv1 = *(const float4*)&maskg[t * 8 + 4];

    const int qrow = w * 16 + g * 4;  // +r
    float rl[4][4];
#pragma unroll
    for (int r = 0; r < 4; ++r)
#pragma unroll
        for (int nt = 0; nt < 4; ++nt)
            rl[r][nt] = relg[(size_t)(qrow + r) * S_ + nt * 16 + lo];

    *(uint4*)&QPs[r0 * 72 + c8]        = qv0;
    *(uint4*)&QPs[(r0 + 32) * 72 + c8] = qv1;
    *(float4*)&Ms[t * 8]     = mv0;
    *(float4*)&Ms[t * 8 + 4] = mv1;

    asm volatile("s_waitcnt lgkmcnt(0)" ::: "memory");
    __builtin_amdgcn_s_barrier();

    // Q A-frags (q pre-scaled by 1/8 in the GEMM). Wave-private strips.
    bf16x8 aq0 = *(const bf16x8*)&QPs[(w * 16 + lo) * 72 + g * 8];
    bf16x8 aq1 = *(const bf16x8*)&QPs[(w * 16 + lo) * 72 + g * 8 + 32];

    float mi[4], li[4];
    f32x4 accO[4];
#pragma unroll
    for (int r = 0; r < 4; ++r) { mi[r] = -1e30f; li[r] = 0.f; }
#pragma unroll
    for (int dt = 0; dt < 4; ++dt) accO[dt] = (f32x4){0.f, 0.f, 0.f, 0.f};

    for (int kc = 0; kc < 32; ++kc) {
        // [write phase] (counted vmcnt inserted by compiler on kv/vv use)
        *(uint4*)&Ks[r0 * 72 + c8]        = kv0;
        *(uint4*)&Ks[(r0 + 32) * 72 + c8] = kv1;
        {
            const unsigned short* vp0 = (const unsigned short*)&vv0;
            const unsigned short* vp1 = (const unsigned short*)&vv1;
            const int s2 = 2 * r0;
#pragma unroll
            for (int j = 0; j < 8; ++j) {
                int d = c8 + j;
                unsigned int pack = (unsigned int)vp0[j] | ((unsigned int)vp1[j] << 16);
                *(unsigned int*)&VTs[d * 72 + (s2 ^ (d & 56))] = pack;
            }
        }
        // issue next K/V chunk loads (in flight across barrier + compute)
        {
            const int kn = (kc < 31) ? kc + 1 : kc;
            const bf16_t* kgn = kg + (size_t)kn * 64 * 64;
            const bf16_t* vgn = vg + (size_t)kn * 64 * 64;
            kv0 = *(const uint4*)&kgn[(size_t)r0 * 64 + c8];
            kv1 = *(const uint4*)&kgn[(size_t)(r0 + 32) * 64 + c8];
            vv0 = *(const uint4*)&vgn[(size_t)(2 * r0) * 64 + c8];
            vv1 = *(const uint4*)&vgn[(size_t)(2 * r0 + 1) * 64 + c8];
        }

        asm volatile("s_waitcnt lgkmcnt(0)" ::: "memory");  // drain ds_writes
        __builtin_amdgcn_s_barrier();                       // tile visible

        // [QK phase]
        f32x4 sc[4];
        __builtin_amdgcn_s_setprio(1);
#pragma unroll
        for (int nt = 0; nt < 4; ++nt) {
            bf16x8 b0 = *(const bf16x8*)&Ks[(nt * 16 + lo) * 72 + g * 8];
            bf16x8 b1 = *(const bf16x8*)&Ks[(nt * 16 + lo) * 72 + g * 8 + 32];
            f32x4 z = (f32x4){0.f, 0.f, 0.f, 0.f};
            z = __builtin_amdgcn_mfma_f32_16x16x32_bf16(aq0, b0, z, 0, 0, 0);
            z = __builtin_amdgcn_mfma_f32_16x16x32_bf16(aq1, b1, z, 0, 0, 0);
            sc[nt] = z;
        }
        __builtin_amdgcn_s_setprio(0);

        // scores = qk + mask(LDS) + rel (reg-prefetched last chunk)
        float sv[4][4];
#pragma unroll
        for (int nt = 0; nt < 4; ++nt) {
            float mk = Ms[kc * 64 + nt * 16 + lo];
#pragma unroll
            for (int r = 0; r < 4; ++r)
                sv[r][nt] = sc[nt][r] + mk + rl[r][nt];
        }

        // issue next chunk's rel loads (hidden under softmax+PV+write phase)
        if (kc < 31) {
#pragma unroll
            for (int r = 0; r < 4; ++r)
#pragma unroll
                for (int nt = 0; nt < 4; ++nt)
                    rl[r][nt] = relg[(size_t)(qrow + r) * S_ + (kc + 1) * 64 + nt * 16 + lo];
        }

        // online softmax; P into this wave's swizzled strip
        bf16_t* Pw = &QPs[w * 16 * 72];
#pragma unroll
        for (int r = 0; r < 4; ++r) {
            float vmax = fmaxf(fmaxf(sv[r][0], sv[r][1]), fmaxf(sv[r][2], sv[r][3]));
#pragma unroll
            for (int mk2 = 1; mk2 < 16; mk2 <<= 1)
                vmax = fmaxf(vmax, __shfl_xor(vmax, mk2, 16));
            float mnew  = fmaxf(mi[r], vmax);
            float alpha = __expf(mi[r] - mnew);
            float rsum = 0.f;
#pragma unroll
            for (int nt = 0; nt < 4; ++nt) {
                float p = __expf(sv[r][nt] - mnew);
                sv[r][nt] = p;
                rsum += p;
            }
#pragma unroll
            for (int mk2 = 1; mk2 < 16; mk2 <<= 1)
                rsum += __shfl_xor(rsum, mk2, 16);
            li[r] = li[r] * alpha + rsum;
            mi[r] = mnew;
#pragma unroll
            for (int dt = 0; dt < 4; ++dt) accO[dt][r] *= alpha;
#pragma unroll
            for (int nt = 0; nt < 4; ++nt)
                Pw[(g * 4 + r) * 72 + ((nt * 16 + lo) ^ (g * 8))] = (bf16_t)sv[r][nt];
        }
        // no barrier: P strip is wave-private; in-wave ds order via lgkmcnt.

        // [PV phase]
        bf16x8 pa0 = *(const bf16x8*)&Pw[lo * 72 + ((g * 8)       ^ ((lo >> 2) * 8))];
        bf16x8 pa1 = *(const bf16x8*)&Pw[lo * 72 + (((4 + g) * 8) ^ ((lo >> 2) * 8))];
        __builtin_amdgcn_s_setprio(1);
#pragma unroll
        for (int dt = 0; dt < 4; ++dt) {
            int d = dt * 16 + lo;
            bf16x8 v0 = *(const bf16x8*)&VTs[d * 72 + ((g * 8)       ^ (d & 56))];
            bf16x8 v1 = *(const bf16x8*)&VTs[d * 72 + (((4 + g) * 8) ^ (d & 56))];
            accO[dt] = __builtin_amdgcn_mfma_f32_16x16x32_bf16(pa0, v0, accO[dt], 0, 0, 0);
            accO[dt] = __builtin_amdgcn_mfma_f32_16x16x32_bf16(pa1, v1, accO[dt], 0, 0, 0);
        }
        __builtin_amdgcn_s_setprio(0);

        // reads retired before next stage overwrites Ks/VTs
        asm volatile("s_waitcnt lgkmcnt(0)" ::: "memory");
        __builtin_amdgcn_s_barrier();
    }

    // epilogue: out[b][s][h*64+d] = O / l
#pragma unroll
    for (int dt = 0; dt < 4; ++dt) {
        int d = dt * 16 + lo;
#pragma unroll
        for (int r = 0; r < 4; ++r) {
            int row = q0 + w * 16 + g * 4 + r;
            out[((size_t)(b * S_ + row)) * H_ + h * HD_ + d] = accO[dt][r] / li[r];
        }
    }
}

extern "C" void kernel_launch(void* const* d_in, const int* in_sizes, int n_in,
                              void* d_out, int out_size, void* d_ws, size_t ws_size,
                              hipStream_t stream) {
    const float* hs   = (const float*)d_in[0];
    const float* mask = (const float*)d_in[1];
    const float* rel  = (const float*)d_in[2];
    const float* Wq   = (const float*)d_in[3];
    const float* bq   = (const float*)d_in[4];
    const float* Wk   = (const float*)d_in[5];
    const float* bk   = (const float*)d_in[6];
    const float* Wv   = (const float*)d_in[7];
    const float* bv   = (const float*)d_in[8];
    float* out = (float*)d_out;

    const size_t qkv_elems = (size_t)B_ * NH_ * S_ * HD_;  // 4,194,304
    bf16_t* qbuf = (bf16_t*)d_ws;
    bf16_t* kbuf = qbuf + qkv_elems;
    bf16_t* vbuf = kbuf + qkv_elems;
    bf16_t* Xb   = vbuf + qkv_elems;               // 4M elems
    bf16_t* Wb   = Xb   + qkv_elems;               // 3M elems (Wq,Wk,Wv)

    cast_bf16<<<7168, 256, 0, stream>>>(hs, Wq, Wk, Wv, Xb, Wb);
    qkv_gemm<<<dim3(32, 8, 3), 256, 0, stream>>>(Xb, Wb, bq, bk, bv,
                                                 qbuf, kbuf, vbuf);
    attn<<<1024, 256, 0, stream>>>(qbuf, kbuf, vbuf, mask, rel, out);
}